// Round 1
// baseline (528.923 us; speedup 1.0000x reference)
//
#include <hip/hip_runtime.h>
#include <math.h>

#define T_DIM 2048
#define B_DIM 8
#define D_DIM 1024
#define N_DIM 64
#define NCHUNK 16
#define CHUNK_LEN 128              // T_DIM / NCHUNK
#define DECAY 0.9f
#define DECAY_L 1.3900845237714473e-06f  // 0.9^128 (double-derived)
#define EPS 1e-8f
#define RADIUS 0.5f

#define BM 128
#define BN 192
#define BK 32

// ---------------- spectral norm scale (2 blocks: k and v) ----------------
__global__ void spectral_kernel(const float* __restrict__ Wk,
                                const float* __restrict__ Wv,
                                const float* __restrict__ uk,
                                const float* __restrict__ uv,
                                float* __restrict__ scale_out) {
    const float* W  = (blockIdx.x == 0) ? Wk : Wv;
    const float* u0 = (blockIdx.x == 0) ? uk : uv;
    __shared__ float u_s[N_DIM];
    __shared__ float v_s[D_DIM];
    __shared__ float t_s[N_DIM];
    __shared__ float red[8];
    int tid = threadIdx.x;       // 256
    int lane = tid & 63;
    int wid = tid >> 6;          // 0..3
    if (tid < N_DIM) u_s[tid] = u0[tid];
    __syncthreads();
    for (int iter = 0; iter < 3; ++iter) {
        // v = W^T u  (each thread owns 4 d-values)
        float vv[4];
        float ss = 0.f;
        #pragma unroll
        for (int e = 0; e < 4; ++e) {
            int d = tid + 256 * e;
            float acc = 0.f;
            for (int nn = 0; nn < N_DIM; ++nn)
                acc += W[nn * D_DIM + d] * u_s[nn];
            vv[e] = acc;
            ss += acc * acc;
        }
        for (int o = 32; o > 0; o >>= 1) ss += __shfl_xor(ss, o, 64);
        if (lane == 0) red[wid] = ss;
        __syncthreads();
        if (tid == 0) {
            float tot = red[0] + red[1] + red[2] + red[3];
            red[4] = 1.0f / (sqrtf(tot) + EPS);
        }
        __syncthreads();
        float inv = red[4];
        #pragma unroll
        for (int e = 0; e < 4; ++e) v_s[tid + 256 * e] = vv[e] * inv;
        __syncthreads();
        // u_raw = W v  (wave wid handles 16 rows)
        for (int rr = 0; rr < 16; ++rr) {
            int r = wid * 16 + rr;
            float acc = 0.f;
            #pragma unroll
            for (int e = 0; e < 16; ++e) {
                int d = lane + 64 * e;
                acc += W[r * D_DIM + d] * v_s[d];
            }
            for (int o = 32; o > 0; o >>= 1) acc += __shfl_xor(acc, o, 64);
            if (lane == 0) t_s[r] = acc;
        }
        __syncthreads();
        if (wid == 0) {
            float val = t_s[lane];
            float s2 = val * val;
            for (int o = 32; o > 0; o >>= 1) s2 += __shfl_xor(s2, o, 64);
            if (lane == 0) red[5] = 1.0f / (sqrtf(s2) + EPS);
        }
        __syncthreads();
        if (tid < N_DIM) u_s[tid] = t_s[tid] * red[5];
        __syncthreads();
    }
    // sigma = |u . (W v)|
    for (int rr = 0; rr < 16; ++rr) {
        int r = wid * 16 + rr;
        float acc = 0.f;
        #pragma unroll
        for (int e = 0; e < 16; ++e) {
            int d = lane + 64 * e;
            acc += W[r * D_DIM + d] * v_s[d];
        }
        for (int o = 32; o > 0; o >>= 1) acc += __shfl_xor(acc, o, 64);
        if (lane == 0) t_s[r] = acc;
    }
    __syncthreads();
    if (wid == 0) {
        float val = t_s[lane] * u_s[lane];
        for (int o = 32; o > 0; o >>= 1) val += __shfl_xor(val, o, 64);
        if (lane == 0) scale_out[blockIdx.x] = RADIUS / (fabsf(val) + EPS);
    }
}

// ------------- build fused, pre-scaled W^T: Wt[d][c], c: 0-63 k, 64-127 v, 128-191 q -------------
__global__ void build_wt_kernel(const float* __restrict__ Wk,
                                const float* __restrict__ Wv,
                                const float* __restrict__ Wq,
                                const float* __restrict__ scale,
                                float* __restrict__ Wt) {
    int d = blockIdx.x;           // 0..1023
    int c = threadIdx.x;          // 0..191
    float val;
    if (c < 64)       val = scale[0] * Wk[c * D_DIM + d];
    else if (c < 128) val = scale[1] * Wv[(c - 64) * D_DIM + d];
    else              val = Wq[(c - 128) * D_DIM + d];
    Wt[d * 192 + c] = val;
}

// ------------- projections: kvq[row][c] = x[row][:] . Wt[:][c], row = t*B+b -------------
__global__ __launch_bounds__(512)
void proj_kernel(const float* __restrict__ x,
                 const float* __restrict__ Wt,
                 float* __restrict__ kvq) {
    __shared__ float xs[BM][BK + 1];     // stride 33: no bank conflict on row reads
    __shared__ float wsh[BK][BN + 2];    // stride 194
    int tid = threadIdx.x;
    int tx = tid & 31;       // col group: cols tx*6 .. tx*6+5
    int ty = tid >> 5;       // 0..15 : rows ty*8 .. ty*8+7
    int rowBase = blockIdx.x * BM;
    float acc[8][6];
    #pragma unroll
    for (int i = 0; i < 8; ++i)
        #pragma unroll
        for (int j = 0; j < 6; ++j) acc[i][j] = 0.f;

    for (int k0 = 0; k0 < D_DIM; k0 += BK) {
        #pragma unroll
        for (int e = 0; e < 8; ++e) {           // 4096 x-elems
            int idx = e * 512 + tid;
            int r = idx >> 5;
            int dd = idx & 31;
            xs[r][dd] = x[(size_t)(rowBase + r) * D_DIM + k0 + dd];
        }
        #pragma unroll
        for (int e = 0; e < 12; ++e) {          // 6144 W-elems
            int idx = e * 512 + tid;
            int kk = idx / 192;
            int c = idx % 192;
            wsh[kk][c] = Wt[(size_t)(k0 + kk) * 192 + c];
        }
        __syncthreads();
        #pragma unroll
        for (int kk = 0; kk < BK; ++kk) {
            float a[8], b[6];
            #pragma unroll
            for (int i = 0; i < 8; ++i) a[i] = xs[ty * 8 + i][kk];
            #pragma unroll
            for (int j = 0; j < 6; ++j) b[j] = wsh[kk][tx * 6 + j];
            #pragma unroll
            for (int i = 0; i < 8; ++i)
                #pragma unroll
                for (int j = 0; j < 6; ++j)
                    acc[i][j] += a[i] * b[j];
        }
        __syncthreads();
    }
    #pragma unroll
    for (int i = 0; i < 8; ++i) {
        int row = rowBase + ty * 8 + i;
        float* dst = &kvq[(size_t)row * 192 + tx * 6];
        #pragma unroll
        for (int j = 0; j < 6; ++j) dst[j] = acc[i][j];
    }
}

// ------------- pass 1: chunk-local final states (zero-init) -------------
__global__ void pass1_kernel(const float* __restrict__ kvq,
                             float* __restrict__ local) {
    int w = (blockIdx.x * blockDim.x + threadIdx.x) >> 6;  // wave id: c*512 + b*64 + i
    int j = threadIdx.x & 63;
    int c = w >> 9;
    int rem = w & 511;
    int b = rem >> 6;
    int i = rem & 63;
    float s = 0.f;
    int t0 = c * CHUNK_LEN;
    for (int t = t0; t < t0 + CHUNK_LEN; ++t) {
        const float* base = kvq + (size_t)(t * B_DIM + b) * 192;
        float k = base[j];
        float v = base[64 + i];
        s = DECAY * s + v * k;
    }
    local[(size_t)w * 64 + j] = s;
}

// ------------- chunk-carry scan (16 steps, thread per (b,i,j)) -------------
__global__ void chunkscan_kernel(const float* __restrict__ local,
                                 float* __restrict__ carry) {
    int e = blockIdx.x * blockDim.x + threadIdx.x;   // 0..32767
    float cy = 0.f;
    #pragma unroll
    for (int c = 0; c < NCHUNK; ++c) {
        carry[c * 32768 + e] = cy;
        cy = DECAY_L * cy + local[c * 32768 + e];
    }
}

// ------------- pass 2: full scan with carry, writes S_all[1..T] and output -------------
__global__ void pass2_kernel(const float* __restrict__ kvq,
                             const float* __restrict__ carry,
                             float* __restrict__ out,      // [T,B,n]
                             float* __restrict__ S_all) {  // [T+1,B,n,n]
    int w = (blockIdx.x * blockDim.x + threadIdx.x) >> 6;  // c*512 + b*64 + i
    int j = threadIdx.x & 63;
    int c = w >> 9;
    int rem = w & 511;
    int b = rem >> 6;
    int i = rem & 63;
    float s = carry[(size_t)w * 64 + j];
    int t0 = c * CHUNK_LEN;
    for (int t = t0; t < t0 + CHUNK_LEN; ++t) {
        const float* base = kvq + (size_t)(t * B_DIM + b) * 192;
        float k = base[j];
        float v = base[64 + i];
        float q = base[128 + j];
        s = DECAY * s + v * k;
        S_all[((size_t)(t + 1) * B_DIM + b) * 4096 + (size_t)i * 64 + j] = s;
        float p = s * q;
        for (int o = 32; o > 0; o >>= 1) p += __shfl_xor(p, o, 64);
        if (j == 0) {
            float sg = 1.0f / (1.0f + __expf(-p));
            out[(t * B_DIM + b) * 64 + i] = p * p * sg;
        }
    }
}

extern "C" void kernel_launch(void* const* d_in, const int* in_sizes, int n_in,
                              void* d_out, int out_size, void* d_ws, size_t ws_size,
                              hipStream_t stream) {
    const float* x  = (const float*)d_in[0];
    const float* S0 = (const float*)d_in[1];
    const float* Wk = (const float*)d_in[2];
    const float* Wv = (const float*)d_in[3];
    const float* Wq = (const float*)d_in[4];
    const float* uk = (const float*)d_in[5];
    const float* uv = (const float*)d_in[6];

    float* out   = (float*)d_out;                              // [T,B,n]
    float* S_all = out + (size_t)T_DIM * B_DIM * N_DIM;        // [T+1,B,n,n]

    float* ws    = (float*)d_ws;
    float* scale = ws;                                  // 2 floats (pad 64)
    float* kvq   = ws + 64;                             // 16384*192
    float* Wt    = kvq + (size_t)16384 * 192;           // 1024*192
    float* local = Wt + (size_t)1024 * 192;             // 16*32768
    float* carry = local + (size_t)NCHUNK * 32768;      // 16*32768

    spectral_kernel<<<2, 256, 0, stream>>>(Wk, Wv, uk, uv, scale);
    build_wt_kernel<<<1024, 192, 0, stream>>>(Wk, Wv, Wq, scale, Wt);
    proj_kernel<<<T_DIM * B_DIM / BM, 512, 0, stream>>>(x, Wt, kvq);
    pass1_kernel<<<NCHUNK * B_DIM * N_DIM / 4, 256, 0, stream>>>(kvq, local);
    chunkscan_kernel<<<B_DIM * N_DIM * N_DIM / 256, 256, 0, stream>>>(local, carry);
    hipMemcpyAsync(S_all, S0, sizeof(float) * B_DIM * N_DIM * N_DIM,
                   hipMemcpyDeviceToDevice, stream);
    pass2_kernel<<<NCHUNK * B_DIM * N_DIM / 4, 256, 0, stream>>>(kvq, carry, out, S_all);
}

// Round 2
// 334.107 us; speedup vs baseline: 1.5831x; 1.5831x over previous
//
#include <hip/hip_runtime.h>
#include <math.h>

#define T_DIM 2048
#define B_DIM 8
#define D_DIM 1024
#define N_DIM 64
#define NCHUNK 16
#define CHUNK_LEN 128              // T_DIM / NCHUNK
#define DECAY 0.9f
#define DECAY_L 1.3900845237714473e-06f  // 0.9^128 (double-derived)
#define EPS 1e-8f
#define RADIUS 0.5f

#define BM 128
#define BN 192
#define BK 32

// ---------------- spectral norm scale (2 blocks: k and v) ----------------
// 1024 threads, fully-unrolled matvec loads (parallel L2 round trips).
__global__ __launch_bounds__(1024)
void spectral_kernel(const float* __restrict__ Wk,
                     const float* __restrict__ Wv,
                     const float* __restrict__ uk,
                     const float* __restrict__ uv,
                     float* __restrict__ scale_out) {
    const float* W  = (blockIdx.x == 0) ? Wk : Wv;
    const float* u0 = (blockIdx.x == 0) ? uk : uv;
    int tid = threadIdx.x;       // 0..1023 = d
    int lane = tid & 63;
    int wid = tid >> 6;          // 0..15
    __shared__ float u_s[N_DIM];
    __shared__ float v_s[D_DIM];
    __shared__ float t_s[N_DIM];
    __shared__ float red[16];
    __shared__ float bcs;
    if (tid < N_DIM) u_s[tid] = u0[tid];
    __syncthreads();
    for (int iter = 0; iter < 3; ++iter) {
        // v_d = W[:,d] . u  — 64 independent loads, unrolled
        float acc = 0.f;
        #pragma unroll
        for (int nn = 0; nn < N_DIM; ++nn)
            acc += W[nn * D_DIM + tid] * u_s[nn];
        // ||v||
        float ss = acc * acc;
        #pragma unroll
        for (int o = 32; o > 0; o >>= 1) ss += __shfl_xor(ss, o, 64);
        if (lane == 0) red[wid] = ss;
        __syncthreads();
        if (tid == 0) {
            float tot = 0.f;
            #pragma unroll
            for (int w2 = 0; w2 < 16; ++w2) tot += red[w2];
            bcs = 1.0f / (sqrtf(tot) + EPS);
        }
        __syncthreads();
        v_s[tid] = acc * bcs;
        __syncthreads();
        // u_raw[r] = W[r,:] . v  — wave handles 4 rows, 16 unrolled loads each
        #pragma unroll
        for (int rr = 0; rr < 4; ++rr) {
            int r = wid * 4 + rr;
            float a = 0.f;
            #pragma unroll
            for (int e = 0; e < 16; ++e)
                a += W[r * D_DIM + lane + 64 * e] * v_s[lane + 64 * e];
            #pragma unroll
            for (int o = 32; o > 0; o >>= 1) a += __shfl_xor(a, o, 64);
            if (lane == 0) t_s[r] = a;
        }
        __syncthreads();
        // normalize u
        if (wid == 0) {
            float uu = t_s[lane];
            float s2 = uu * uu;
            #pragma unroll
            for (int o = 32; o > 0; o >>= 1) s2 += __shfl_xor(s2, o, 64);
            float inv = 1.0f / (sqrtf(__shfl(s2, 0, 64)) + EPS);
            u_s[lane] = uu * inv;
        }
        __syncthreads();
    }
    // sigma = |u . (W v)| ; t_s still holds W v from the last iteration
    if (wid == 0) {
        float val = t_s[lane] * u_s[lane];
        #pragma unroll
        for (int o = 32; o > 0; o >>= 1) val += __shfl_xor(val, o, 64);
        if (lane == 0) scale_out[blockIdx.x] = RADIUS / (fabsf(val) + EPS);
    }
}

// ------------- build fused, pre-scaled W^T: Wt[d][c], c: 0-63 k, 64-127 v, 128-191 q -------------
__global__ void build_wt_kernel(const float* __restrict__ Wk,
                                const float* __restrict__ Wv,
                                const float* __restrict__ Wq,
                                const float* __restrict__ scale,
                                float* __restrict__ Wt) {
    int d = blockIdx.x;           // 0..1023
    int c = threadIdx.x;          // 0..191
    float val;
    if (c < 64)       val = scale[0] * Wk[c * D_DIM + d];
    else if (c < 128) val = scale[1] * Wv[(c - 64) * D_DIM + d];
    else              val = Wq[(c - 128) * D_DIM + d];
    Wt[d * 192 + c] = val;
}

// ------------- projections: kvq[row][c] = x[row][:] . Wt[:][c], row = t*B+b -------------
__global__ __launch_bounds__(512)
void proj_kernel(const float* __restrict__ x,
                 const float* __restrict__ Wt,
                 float* __restrict__ kvq) {
    __shared__ float xs[BM][BK + 1];     // stride 33: no bank conflict on row reads
    __shared__ float wsh[BK][BN + 2];    // stride 194
    int tid = threadIdx.x;
    int tx = tid & 31;       // col group: cols tx*6 .. tx*6+5
    int ty = tid >> 5;       // 0..15 : rows ty*8 .. ty*8+7
    int rowBase = blockIdx.x * BM;
    float acc[8][6];
    #pragma unroll
    for (int i = 0; i < 8; ++i)
        #pragma unroll
        for (int j = 0; j < 6; ++j) acc[i][j] = 0.f;

    for (int k0 = 0; k0 < D_DIM; k0 += BK) {
        #pragma unroll
        for (int e = 0; e < 8; ++e) {           // 4096 x-elems
            int idx = e * 512 + tid;
            int r = idx >> 5;
            int dd = idx & 31;
            xs[r][dd] = x[(size_t)(rowBase + r) * D_DIM + k0 + dd];
        }
        #pragma unroll
        for (int e = 0; e < 12; ++e) {          // 6144 W-elems
            int idx = e * 512 + tid;
            int kk = idx / 192;
            int c = idx % 192;
            wsh[kk][c] = Wt[(size_t)(k0 + kk) * 192 + c];
        }
        __syncthreads();
        #pragma unroll
        for (int kk = 0; kk < BK; ++kk) {
            float a[8], b[6];
            #pragma unroll
            for (int i = 0; i < 8; ++i) a[i] = xs[ty * 8 + i][kk];
            #pragma unroll
            for (int j = 0; j < 6; ++j) b[j] = wsh[kk][tx * 6 + j];
            #pragma unroll
            for (int i = 0; i < 8; ++i)
                #pragma unroll
                for (int j = 0; j < 6; ++j)
                    acc[i][j] += a[i] * b[j];
        }
        __syncthreads();
    }
    #pragma unroll
    for (int i = 0; i < 8; ++i) {
        int row = rowBase + ty * 8 + i;
        float* dst = &kvq[(size_t)row * 192 + tx * 6];
        #pragma unroll
        for (int j = 0; j < 6; ++j) dst[j] = acc[i][j];
    }
}

// ------------- pass 1: chunk-local final states (zero-init) -------------
__global__ void pass1_kernel(const float* __restrict__ kvq,
                             float* __restrict__ local) {
    int w = (blockIdx.x * blockDim.x + threadIdx.x) >> 6;  // wave id: c*512 + b*64 + i
    int j = threadIdx.x & 63;
    int c = w >> 9;
    int rem = w & 511;
    int b = rem >> 6;
    int i = rem & 63;
    float s = 0.f;
    int t0 = c * CHUNK_LEN;
    for (int t = t0; t < t0 + CHUNK_LEN; ++t) {
        const float* base = kvq + (size_t)(t * B_DIM + b) * 192;
        float k = base[j];
        float v = base[64 + i];
        s = DECAY * s + v * k;
    }
    local[(size_t)w * 64 + j] = s;
}

// ------------- chunk-carry scan (16 steps, thread per (b,i,j)) -------------
__global__ void chunkscan_kernel(const float* __restrict__ local,
                                 float* __restrict__ carry) {
    int e = blockIdx.x * blockDim.x + threadIdx.x;   // 0..32767
    float cy = 0.f;
    #pragma unroll
    for (int c = 0; c < NCHUNK; ++c) {
        carry[c * 32768 + e] = cy;
        cy = DECAY_L * cy + local[c * 32768 + e];
    }
}

// ------------- pass 2: full scan with carry, writes S_all[1..T] and output -------------
// Batched output reduction: buffer 16 t-steps of p in a per-wave LDS tile,
// transpose-read (padded, conflict-free b128) and reduce with 2 shuffles per
// 16 steps instead of 6 shuffles per step.
#define P2_WAVES 4
__global__ __launch_bounds__(256)
void pass2_kernel(const float* __restrict__ kvq,
                  const float* __restrict__ carry,
                  float* __restrict__ out,      // [T,B,n]
                  float* __restrict__ S_all) {  // [T+1,B,n,n]
    __shared__ __align__(16) float P[P2_WAVES][16][68];   // padded: conflict-free b128 reads
    int widL = threadIdx.x >> 6;                 // wave in block
    int j = threadIdx.x & 63;
    int w = blockIdx.x * P2_WAVES + widL;        // global wave id: c*512 + b*64 + i
    int c = w >> 9;
    int rem = w & 511;
    int b = rem >> 6;
    int i = rem & 63;
    int tl = j & 15;          // t-slot this lane reduces
    int part = j >> 4;        // 16-column slice this lane sums

    float s = carry[(size_t)w * 64 + j];
    int t0 = c * CHUNK_LEN;
    for (int tb = 0; tb < CHUNK_LEN; tb += 16) {
        #pragma unroll
        for (int u = 0; u < 16; ++u) {
            int t = t0 + tb + u;
            const float* base = kvq + (size_t)(t * B_DIM + b) * 192;
            float k = base[j];
            float v = base[64 + i];
            float q = base[128 + j];
            s = __builtin_fmaf(DECAY, s, v * k);
            S_all[((size_t)(t + 1) * B_DIM + b) * 4096 + (size_t)i * 64 + j] = s;
            P[widL][u][j] = s * q;               // b32, lanes consecutive: conflict-free
        }
        // reduce the 16 buffered rows: lane (tl,part) sums P[tl][part*16 .. +15]
        float acc = 0.f;
        #pragma unroll
        for (int rd = 0; rd < 4; ++rd) {
            const float4 a = *(const float4*)&P[widL][tl][part * 16 + rd * 4];
            acc += (a.x + a.y) + (a.z + a.w);
        }
        acc += __shfl_xor(acc, 16, 64);
        acc += __shfl_xor(acc, 32, 64);
        if (part == 0) {
            int t = t0 + tb + tl;
            float sg = 1.0f / (1.0f + __expf(-acc));
            out[(t * B_DIM + b) * 64 + i] = acc * acc * sg;
        }
    }
}

extern "C" void kernel_launch(void* const* d_in, const int* in_sizes, int n_in,
                              void* d_out, int out_size, void* d_ws, size_t ws_size,
                              hipStream_t stream) {
    const float* x  = (const float*)d_in[0];
    const float* S0 = (const float*)d_in[1];
    const float* Wk = (const float*)d_in[2];
    const float* Wv = (const float*)d_in[3];
    const float* Wq = (const float*)d_in[4];
    const float* uk = (const float*)d_in[5];
    const float* uv = (const float*)d_in[6];

    float* out   = (float*)d_out;                              // [T,B,n]
    float* S_all = out + (size_t)T_DIM * B_DIM * N_DIM;        // [T+1,B,n,n]

    float* ws    = (float*)d_ws;
    float* scale = ws;                                  // 2 floats (pad 64)
    float* kvq   = ws + 64;                             // 16384*192
    float* Wt    = kvq + (size_t)16384 * 192;           // 1024*192
    float* local = Wt + (size_t)1024 * 192;             // 16*32768
    float* carry = local + (size_t)NCHUNK * 32768;      // 16*32768

    spectral_kernel<<<2, 1024, 0, stream>>>(Wk, Wv, uk, uv, scale);
    build_wt_kernel<<<1024, 192, 0, stream>>>(Wk, Wv, Wq, scale, Wt);
    proj_kernel<<<T_DIM * B_DIM / BM, 512, 0, stream>>>(x, Wt, kvq);
    pass1_kernel<<<NCHUNK * B_DIM * N_DIM / 4, 256, 0, stream>>>(kvq, local);
    chunkscan_kernel<<<B_DIM * N_DIM * N_DIM / 256, 256, 0, stream>>>(local, carry);
    hipMemcpyAsync(S_all, S0, sizeof(float) * B_DIM * N_DIM * N_DIM,
                   hipMemcpyDeviceToDevice, stream);
    pass2_kernel<<<NCHUNK * B_DIM * N_DIM / 4, 256, 0, stream>>>(kvq, carry, out, S_all);
}

// Round 3
// 216.301 us; speedup vs baseline: 2.4453x; 1.5446x over previous
//
#include <hip/hip_runtime.h>
#include <math.h>

#define T_DIM 2048
#define B_DIM 8
#define D_DIM 1024
#define N_DIM 64
#define NCHUNK 16
#define CHUNK_LEN 128              // T_DIM / NCHUNK
#define DECAY 0.9f
#define DECAY_L 1.3900845237714473e-06f  // 0.9^128 (double-derived)
#define EPS 1e-8f
#define RADIUS 0.5f

typedef __attribute__((ext_vector_type(8))) short short8;   // bf16x8 MFMA frag
typedef __attribute__((ext_vector_type(4))) float f32x4;

static __device__ __forceinline__ unsigned short f2bf(float f) {
    unsigned u = __float_as_uint(f);
    u += 0x7FFFu + ((u >> 16) & 1u);          // RNE
    return (unsigned short)(u >> 16);
}
static __device__ __forceinline__ float bf2f(unsigned short h) {
    return __uint_as_float(((unsigned)h) << 16);
}

// ---------------- spectral norm scale (2 blocks: k and v) ----------------
__global__ __launch_bounds__(1024)
void spectral_kernel(const float* __restrict__ Wk,
                     const float* __restrict__ Wv,
                     const float* __restrict__ uk,
                     const float* __restrict__ uv,
                     float* __restrict__ scale_out) {
    const float* W  = (blockIdx.x == 0) ? Wk : Wv;
    const float* u0 = (blockIdx.x == 0) ? uk : uv;
    int tid = threadIdx.x;       // 0..1023 = d
    int lane = tid & 63;
    int wid = tid >> 6;          // 0..15
    __shared__ float u_s[N_DIM];
    __shared__ float v_s[D_DIM];
    __shared__ float t_s[N_DIM];
    __shared__ float red[16];
    __shared__ float bcs;
    if (tid < N_DIM) u_s[tid] = u0[tid];
    __syncthreads();
    for (int iter = 0; iter < 3; ++iter) {
        float acc = 0.f;
        #pragma unroll
        for (int nn = 0; nn < N_DIM; ++nn)
            acc += W[nn * D_DIM + tid] * u_s[nn];
        float ss = acc * acc;
        #pragma unroll
        for (int o = 32; o > 0; o >>= 1) ss += __shfl_xor(ss, o, 64);
        if (lane == 0) red[wid] = ss;
        __syncthreads();
        if (tid == 0) {
            float tot = 0.f;
            #pragma unroll
            for (int w2 = 0; w2 < 16; ++w2) tot += red[w2];
            bcs = 1.0f / (sqrtf(tot) + EPS);
        }
        __syncthreads();
        v_s[tid] = acc * bcs;
        __syncthreads();
        #pragma unroll
        for (int rr = 0; rr < 4; ++rr) {
            int r = wid * 4 + rr;
            float a = 0.f;
            #pragma unroll
            for (int e = 0; e < 16; ++e)
                a += W[r * D_DIM + lane + 64 * e] * v_s[lane + 64 * e];
            #pragma unroll
            for (int o = 32; o > 0; o >>= 1) a += __shfl_xor(a, o, 64);
            if (lane == 0) t_s[r] = a;
        }
        __syncthreads();
        if (wid == 0) {
            float uu = t_s[lane];
            float s2 = uu * uu;
            #pragma unroll
            for (int o = 32; o > 0; o >>= 1) s2 += __shfl_xor(s2, o, 64);
            float inv = 1.0f / (sqrtf(__shfl(s2, 0, 64)) + EPS);
            u_s[lane] = uu * inv;
        }
        __syncthreads();
    }
    if (wid == 0) {
        float val = t_s[lane] * u_s[lane];
        #pragma unroll
        for (int o = 32; o > 0; o >>= 1) val += __shfl_xor(val, o, 64);
        if (lane == 0) scale_out[blockIdx.x] = RADIUS / (fabsf(val) + EPS);
    }
}

// ------- build bf16 hi/lo of fused scaled W, stored row-major [c][k] (c: k|v|q) -------
__global__ __launch_bounds__(256)
void build_wt_kernel(const float* __restrict__ Wk,
                     const float* __restrict__ Wv,
                     const float* __restrict__ Wq,
                     const float* __restrict__ scale,
                     unsigned short* __restrict__ Wth,
                     unsigned short* __restrict__ Wtl) {
    int c = blockIdx.x;           // 0..191
    int t = threadIdx.x;          // 0..255, 4 elems each
    const float* src;
    float sc;
    if (c < 64)       { src = Wk + (size_t)c * D_DIM;         sc = scale[0]; }
    else if (c < 128) { src = Wv + (size_t)(c - 64) * D_DIM;  sc = scale[1]; }
    else              { src = Wq + (size_t)(c - 128) * D_DIM; sc = 1.0f; }
    float4 w = *(const float4*)(src + t * 4);
    float vals[4] = {w.x * sc, w.y * sc, w.z * sc, w.w * sc};
    unsigned short h[4], l[4];
    #pragma unroll
    for (int e = 0; e < 4; ++e) {
        h[e] = f2bf(vals[e]);
        l[e] = f2bf(vals[e] - bf2f(h[e]));
    }
    size_t base = (size_t)c * D_DIM + t * 4;
    *(ushort4*)(Wth + base) = make_ushort4(h[0], h[1], h[2], h[3]);
    *(ushort4*)(Wtl + base) = make_ushort4(l[0], l[1], l[2], l[3]);
}

// ------------- projections via split-bf16 MFMA: kvq = x . Wt^T -------------
// BM=32 rows/block, 512 blocks (2/CU). 4 waves: wave wv does cols [wv*48, +48).
// x staged fp32->LDS as XOR-swizzled bf16 hi/lo, double-buffered, reg prefetch.
// B-frags read from global (L2-resident, 768 KB total).
#define PBM 32
#define PBK 64
__global__ __launch_bounds__(256)
void proj_mfma_kernel(const float* __restrict__ x,
                      const unsigned short* __restrict__ Wth,
                      const unsigned short* __restrict__ Wtl,
                      float* __restrict__ kvq) {
    __shared__ __align__(16) unsigned short lds[2][2][PBM * PBK];  // [buf][h/l] 16 KB
    int tid = threadIdx.x;
    int lane = tid & 63;
    int wv = tid >> 6;                 // 0..3
    int fl15 = lane & 15;
    int flh = lane >> 4;               // 0..3
    int rowBase = blockIdx.x * PBM;

    // staging: thread t handles row t>>3, 8 floats at col (t&7)*8
    int r_st = tid >> 3;
    int c_st = (tid & 7) * 8;
    const float* xrow = x + (size_t)(rowBase + r_st) * D_DIM + c_st;
    int wr_off = (r_st * 128 + (tid & 7) * 16) ^ ((r_st & 7) << 4);  // bytes

    // B-frag base pointers (lane-resolved)
    size_t boff = (size_t)(wv * 48 + fl15) * D_DIM + flh * 8;
    const unsigned short* bph = Wth + boff;
    const unsigned short* bpl = Wtl + boff;

    f32x4 acc[2][3];
    #pragma unroll
    for (int mt = 0; mt < 2; ++mt)
        #pragma unroll
        for (int nt = 0; nt < 3; ++nt) acc[mt][nt] = (f32x4)(0.f);

    // prologue: stage s=0
    {
        float4 a = *(const float4*)(xrow);
        float4 b = *(const float4*)(xrow + 4);
        float v[8] = {a.x, a.y, a.z, a.w, b.x, b.y, b.z, b.w};
        short8 hv, lv;
        #pragma unroll
        for (int e = 0; e < 8; ++e) {
            unsigned short hh = f2bf(v[e]);
            hv[e] = (short)hh;
            lv[e] = (short)f2bf(v[e] - bf2f(hh));
        }
        *(short8*)((char*)&lds[0][0][0] + wr_off) = hv;
        *(short8*)((char*)&lds[0][1][0] + wr_off) = lv;
    }
    __syncthreads();

    for (int s = 0; s < 16; ++s) {
        int k0 = s * PBK;
        // prefetch next x tile to regs
        float4 na, nb;
        if (s < 15) {
            na = *(const float4*)(xrow + k0 + PBK);
            nb = *(const float4*)(xrow + k0 + PBK + 4);
        }
        // B fragments for this K-step (12 x 16B global loads, L2-hit)
        short8 bh[2][3], bl[2][3];
        #pragma unroll
        for (int kh = 0; kh < 2; ++kh)
            #pragma unroll
            for (int nt = 0; nt < 3; ++nt) {
                bh[kh][nt] = *(const short8*)(bph + (size_t)nt * 16 * D_DIM + k0 + kh * 32);
                bl[kh][nt] = *(const short8*)(bpl + (size_t)nt * 16 * D_DIM + k0 + kh * 32);
            }
        const char* ldsH = (const char*)&lds[s & 1][0][0];
        const char* ldsL = (const char*)&lds[s & 1][1][0];
        #pragma unroll
        for (int kh = 0; kh < 2; ++kh) {
            short8 ah[2], al[2];
            #pragma unroll
            for (int mt = 0; mt < 2; ++mt) {
                int row = mt * 16 + fl15;
                int off = (row * 128 + kh * 64 + flh * 16) ^ ((row & 7) << 4);
                ah[mt] = *(const short8*)(ldsH + off);
                al[mt] = *(const short8*)(ldsL + off);
            }
            #pragma unroll
            for (int mt = 0; mt < 2; ++mt)
                #pragma unroll
                for (int nt = 0; nt < 3; ++nt) {
                    acc[mt][nt] = __builtin_amdgcn_mfma_f32_16x16x32_bf16(
                        ah[mt], bh[kh][nt], acc[mt][nt], 0, 0, 0);
                    acc[mt][nt] = __builtin_amdgcn_mfma_f32_16x16x32_bf16(
                        ah[mt], bl[kh][nt], acc[mt][nt], 0, 0, 0);
                    acc[mt][nt] = __builtin_amdgcn_mfma_f32_16x16x32_bf16(
                        al[mt], bh[kh][nt], acc[mt][nt], 0, 0, 0);
                }
        }
        // stage next tile into the other buffer
        if (s < 15) {
            float v[8] = {na.x, na.y, na.z, na.w, nb.x, nb.y, nb.z, nb.w};
            short8 hv, lv;
            #pragma unroll
            for (int e = 0; e < 8; ++e) {
                unsigned short hh = f2bf(v[e]);
                hv[e] = (short)hh;
                lv[e] = (short)f2bf(v[e] - bf2f(hh));
            }
            *(short8*)((char*)&lds[(s + 1) & 1][0][0] + wr_off) = hv;
            *(short8*)((char*)&lds[(s + 1) & 1][1][0] + wr_off) = lv;
        }
        __syncthreads();
    }

    // epilogue: C/D layout col=lane&15, row=(lane>>4)*4+reg  [m89]
    #pragma unroll
    for (int mt = 0; mt < 2; ++mt)
        #pragma unroll
        for (int nt = 0; nt < 3; ++nt) {
            int col = wv * 48 + nt * 16 + fl15;
            #pragma unroll
            for (int r = 0; r < 4; ++r) {
                int row = rowBase + mt * 16 + flh * 4 + r;
                kvq[(size_t)row * 192 + col] = acc[mt][nt][r];
            }
        }
}

// ------------- pass 1: chunk-local final states (zero-init) -------------
__global__ void pass1_kernel(const float* __restrict__ kvq,
                             float* __restrict__ local) {
    int w = (blockIdx.x * blockDim.x + threadIdx.x) >> 6;  // wave id: c*512 + b*64 + i
    int j = threadIdx.x & 63;
    int c = w >> 9;
    int rem = w & 511;
    int b = rem >> 6;
    int i = rem & 63;
    float s = 0.f;
    int t0 = c * CHUNK_LEN;
    for (int t = t0; t < t0 + CHUNK_LEN; ++t) {
        const float* base = kvq + (size_t)(t * B_DIM + b) * 192;
        float k = base[j];
        float v = base[64 + i];
        s = DECAY * s + v * k;
    }
    local[(size_t)w * 64 + j] = s;
}

// ------------- chunk-carry scan (16 steps, thread per (b,i,j)) -------------
__global__ void chunkscan_kernel(const float* __restrict__ local,
                                 float* __restrict__ carry) {
    int e = blockIdx.x * blockDim.x + threadIdx.x;   // 0..32767
    float cy = 0.f;
    #pragma unroll
    for (int c = 0; c < NCHUNK; ++c) {
        carry[c * 32768 + e] = cy;
        cy = DECAY_L * cy + local[c * 32768 + e];
    }
}

// ------------- pass 2: full scan with carry, writes S_all[1..T] and output -------------
#define P2_WAVES 4
__global__ __launch_bounds__(256)
void pass2_kernel(const float* __restrict__ kvq,
                  const float* __restrict__ carry,
                  float* __restrict__ out,      // [T,B,n]
                  float* __restrict__ S_all) {  // [T+1,B,n,n]
    __shared__ __align__(16) float P[P2_WAVES][16][68];   // padded: conflict-free reads
    int widL = threadIdx.x >> 6;                 // wave in block
    int j = threadIdx.x & 63;
    int w = blockIdx.x * P2_WAVES + widL;        // global wave id: c*512 + b*64 + i
    int c = w >> 9;
    int rem = w & 511;
    int b = rem >> 6;
    int i = rem & 63;
    int tl = j & 15;          // t-slot this lane reduces
    int part = j >> 4;        // 16-column slice this lane sums

    float s = carry[(size_t)w * 64 + j];
    int t0 = c * CHUNK_LEN;
    for (int tb = 0; tb < CHUNK_LEN; tb += 16) {
        #pragma unroll
        for (int u = 0; u < 16; ++u) {
            int t = t0 + tb + u;
            const float* base = kvq + (size_t)(t * B_DIM + b) * 192;
            float k = base[j];
            float v = base[64 + i];
            float q = base[128 + j];
            s = __builtin_fmaf(DECAY, s, v * k);
            S_all[((size_t)(t + 1) * B_DIM + b) * 4096 + (size_t)i * 64 + j] = s;
            P[widL][u][j] = s * q;
        }
        float acc = 0.f;
        #pragma unroll
        for (int rd = 0; rd < 4; ++rd) {
            const float4 a = *(const float4*)&P[widL][tl][part * 16 + rd * 4];
            acc += (a.x + a.y) + (a.z + a.w);
        }
        acc += __shfl_xor(acc, 16, 64);
        acc += __shfl_xor(acc, 32, 64);
        if (part == 0) {
            int t = t0 + tb + tl;
            float sg = 1.0f / (1.0f + __expf(-acc));
            out[(t * B_DIM + b) * 64 + i] = acc * acc * sg;
        }
    }
}

extern "C" void kernel_launch(void* const* d_in, const int* in_sizes, int n_in,
                              void* d_out, int out_size, void* d_ws, size_t ws_size,
                              hipStream_t stream) {
    const float* x  = (const float*)d_in[0];
    const float* S0 = (const float*)d_in[1];
    const float* Wk = (const float*)d_in[2];
    const float* Wv = (const float*)d_in[3];
    const float* Wq = (const float*)d_in[4];
    const float* uk = (const float*)d_in[5];
    const float* uv = (const float*)d_in[6];

    float* out   = (float*)d_out;                              // [T,B,n]
    float* S_all = out + (size_t)T_DIM * B_DIM * N_DIM;        // [T+1,B,n,n]

    float* ws    = (float*)d_ws;
    float* scale = ws;                                   // 2 floats (pad 64)
    float* kvq   = ws + 64;                              // 16384*192
    unsigned short* Wth = (unsigned short*)(kvq + (size_t)16384 * 192);  // 192*1024
    unsigned short* Wtl = Wth + (size_t)192 * D_DIM;
    float* local = (float*)(Wtl + (size_t)192 * D_DIM); // 16*32768
    float* carry = local + (size_t)NCHUNK * 32768;       // 16*32768

    spectral_kernel<<<2, 1024, 0, stream>>>(Wk, Wv, uk, uv, scale);
    build_wt_kernel<<<192, 256, 0, stream>>>(Wk, Wv, Wq, scale, Wth, Wtl);
    proj_mfma_kernel<<<T_DIM * B_DIM / PBM, 256, 0, stream>>>(x, Wth, Wtl, kvq);
    pass1_kernel<<<NCHUNK * B_DIM * N_DIM / 4, 256, 0, stream>>>(kvq, local);
    chunkscan_kernel<<<B_DIM * N_DIM * N_DIM / 256, 256, 0, stream>>>(local, carry);
    hipMemcpyAsync(S_all, S0, sizeof(float) * B_DIM * N_DIM * N_DIM,
                   hipMemcpyDeviceToDevice, stream);
    pass2_kernel<<<NCHUNK * B_DIM * N_DIM / 4, 256, 0, stream>>>(kvq, carry, out, S_all);
}